// Round 2
// baseline (11042.496 us; speedup 1.0000x reference)
//
#include <hip/hip_runtime.h>

#define N_SEQ  257
#define BATCH  64
#define CDIM   768
#define HEADS  12
#define HDIM   64
#define HIDDEN 3072
#define MROWS  (BATCH * N_SEQ)   // 16448

typedef unsigned short u16;
typedef unsigned int   u32;
typedef __bf16 bf16x8 __attribute__((ext_vector_type(8)));
typedef float  f32x4  __attribute__((ext_vector_type(4)));

__device__ __forceinline__ float b2f(u16 u) { u32 x = ((u32)u) << 16; return __uint_as_float(x); }
__device__ __forceinline__ u16   f2b(float f) {
    u32 x = __float_as_uint(f);
    u32 r = (x + 0x7fffu + ((x >> 16) & 1u)) >> 16;  // round-nearest-even
    return (u16)r;
}
__device__ __forceinline__ float ldf(const float x) { return x; }
__device__ __forceinline__ float ldf(const u16 x)   { return b2f(x); }

__device__ __forceinline__ float geluf(float x) { return 0.5f * x * (1.f + erff(x * 0.70710678118654752f)); }
// arf(x) = (e^x - e^-x)/(e^x + e^-x-4); negative clamped to 0. For x>0 multiply
// num/den by e^-x: (1 - e^-2x)/(1 + e^-2x-4) -- overflow-proof for all finite x.
__device__ __forceinline__ float arff(float x) {
    if (x <= 0.f) return 0.f;
    float a = expf(-2.f * x);
    float c = expf(-2.f * x - 4.f);
    return (1.f - a) / (1.f + c);
}

template<bool MAXOP>
__device__ __forceinline__ float block_red(float v, float* scratch, int tid) {
#pragma unroll
    for (int off = 32; off > 0; off >>= 1) {
        float o = __shfl_down(v, off, 64);
        v = MAXOP ? fmaxf(v, o) : v + o;
    }
    if ((tid & 63) == 0) scratch[tid >> 6] = v;
    __syncthreads();
    float r = MAXOP ? fmaxf(fmaxf(scratch[0], scratch[1]), fmaxf(scratch[2], scratch[3]))
                    : (scratch[0] + scratch[1]) + (scratch[2] + scratch[3]);
    __syncthreads();
    return r;
}

// ---------------------------------------------------------------------------
// dtype detection: norm1_g is all-ones. bf16(1.0) halfword = 0x3F80;
// fp32(1.0f) low halfword = 0x0000. flag: 1 = bf16 inputs, 0 = fp32 inputs.
// ---------------------------------------------------------------------------
__global__ void detect_kernel(const u16* __restrict__ g1, u32* __restrict__ flag)
{
    if (threadIdx.x == 0 && blockIdx.x == 0) *flag = (g1[0] == 0x3F80u) ? 1u : 0u;
}

__global__ __launch_bounds__(256)
void conv_kernel(const void* __restrict__ s, u16* __restrict__ d, int n,
                 const u32* __restrict__ flag)
{
    const int i = blockIdx.x * 256 + threadIdx.x;
    if (i >= n) return;
    if (*flag) d[i] = ((const u16*)s)[i];
    else       d[i] = f2b(((const float*)s)[i]);
}

// ---------------------------------------------------------------------------
// GEMM: out[m, n] = sum_k A[m,k] * W[n,k]   (A: MxK bf16, W: NxK bf16)
// 128x128 tile, BK=32, 4 waves each computing 64x64 via 4x4 mfma 16x16x32.
// EP: 0 plain(+bias), 1 gelu(+bias), 2 bias+write C+resid+=, 3 arf+write C+resid+=, 4 bias+resid+= only
// ---------------------------------------------------------------------------
#define LDSW 40   // padded LDS row stride in bf16 (80 B, 16B aligned, breaks bank conflicts)

template<int EP>
__global__ __launch_bounds__(256)
void gemm_kernel(const u16* __restrict__ A, const u16* __restrict__ W,
                 const u16* __restrict__ bias, u16* __restrict__ Co,
                 float* __restrict__ resid, int M, int Ncols, int K)
{
    __shared__ __align__(16) u16 sA[128 * LDSW];
    __shared__ __align__(16) u16 sB[128 * LDSW];
    const int tid  = threadIdx.x;
    const int bm0  = blockIdx.y * 128;
    const int n0   = blockIdx.x * 128;
    const int lane = tid & 63, wave = tid >> 6;
    const int wm = (wave >> 1) << 6;   // 0 / 64
    const int wn = (wave & 1) << 6;    // 0 / 64
    const int r16 = lane & 15, quad = lane >> 4;

    f32x4 acc[4][4] = {};

    for (int k0 = 0; k0 < K; k0 += 32) {
        __syncthreads();
#pragma unroll
        for (int it = 0; it < 2; ++it) {
            int c2  = tid + (it << 8);
            int row = c2 >> 2;
            int col = (c2 & 3) << 3;
            int gm  = bm0 + row; if (gm >= M) gm = M - 1;   // clamp (dup row; unused outputs guarded)
            *reinterpret_cast<uint4*>(&sA[row * LDSW + col]) =
                *reinterpret_cast<const uint4*>(A + (size_t)gm * K + k0 + col);
            *reinterpret_cast<uint4*>(&sB[row * LDSW + col]) =
                *reinterpret_cast<const uint4*>(W + (size_t)(n0 + row) * K + k0 + col);
        }
        __syncthreads();

        bf16x8 af[4], bfr[4];
#pragma unroll
        for (int i = 0; i < 4; ++i) {
            af[i]  = *reinterpret_cast<const bf16x8*>(&sA[(wm + i * 16 + r16) * LDSW + quad * 8]);
            bfr[i] = *reinterpret_cast<const bf16x8*>(&sB[(wn + i * 16 + r16) * LDSW + quad * 8]);
        }
#pragma unroll
        for (int i = 0; i < 4; ++i)
#pragma unroll
            for (int j = 0; j < 4; ++j)
                acc[i][j] = __builtin_amdgcn_mfma_f32_16x16x32_bf16(af[i], bfr[j], acc[i][j], 0, 0, 0);
    }

    // epilogue: lane holds D[row = quad*4+reg][col = lane&15] per 16x16 tile
#pragma unroll
    for (int i = 0; i < 4; ++i) {
#pragma unroll
        for (int j = 0; j < 4; ++j) {
            const int gn = n0 + wn + j * 16 + r16;
            const float bv = bias ? b2f(bias[gn]) : 0.f;
#pragma unroll
            for (int r = 0; r < 4; ++r) {
                const int gm = bm0 + wm + i * 16 + quad * 4 + r;
                if (gm < M) {
                    float v = acc[i][j][r] + bv;
                    const size_t oidx = (size_t)gm * Ncols + gn;
                    if (EP == 1) v = geluf(v);
                    if (EP == 3) v = arff(v);
                    if (EP == 0 || EP == 1) Co[oidx] = f2b(v);
                    if (EP == 2 || EP == 3) { Co[oidx] = f2b(v); resid[oidx] += v; }
                    if (EP == 4) resid[oidx] += v;
                }
            }
        }
    }
}

// ---------------------------------------------------------------------------
// LayerNorm over C=768; one block per row; input fp32 or bf16, output bf16
// ---------------------------------------------------------------------------
template<typename T>
__global__ __launch_bounds__(256)
void ln_kernel(const T* __restrict__ x, const u16* __restrict__ g,
               const u16* __restrict__ be, u16* __restrict__ y)
{
    __shared__ float scratch[4];
    const int row = blockIdx.x, tid = threadIdx.x;
    const size_t base = (size_t)row * CDIM;
    float v[3];
#pragma unroll
    for (int i = 0; i < 3; ++i) v[i] = ldf(x[base + tid + i * 256]);
    float mean = block_red<false>(v[0] + v[1] + v[2], scratch, tid) * (1.f / 768.f);
    float d0 = v[0] - mean, d1 = v[1] - mean, d2 = v[2] - mean;
    float var = block_red<false>(d0 * d0 + d1 * d1 + d2 * d2, scratch, tid) * (1.f / 768.f);
    float rstd = rsqrtf(var + 1e-5f);
#pragma unroll
    for (int i = 0; i < 3; ++i) {
        int c = tid + i * 256;
        y[base + c] = f2b((v[i] - mean) * rstd * b2f(g[c]) + b2f(be[c]));
    }
}

// ---------------------------------------------------------------------------
// Attention: one block per (h, b). K staged to LDS (stride 66 = conflict-free),
// V read from global. fp32 softmax. O[b,n, h*64+d]; optional asum[b,n,m] += p.
// ---------------------------------------------------------------------------
__global__ __launch_bounds__(256)
void attn_kernel(const u16* __restrict__ Q, int qs,
                 const u16* __restrict__ Kp, int ks,
                 const u16* __restrict__ Vp, int vs,
                 u16* __restrict__ O, float* __restrict__ asum)
{
    __shared__ __align__(16) u16 Ks[N_SEQ * 66];
    __shared__ u16  qsm[64];
    __shared__ float sc[N_SEQ];
    __shared__ float red[256];
    __shared__ float scratch[4];
    const int tid = threadIdx.x;
    const int h = blockIdx.x, b = blockIdx.y;

    for (int i = tid; i < N_SEQ * 32; i += 256) {      // 32 dwords per 64-el row
        int r = i >> 5, c = i & 31;
        reinterpret_cast<u32*>(Ks)[r * 33 + c] =
            reinterpret_cast<const u32*>(Kp + (size_t)(b * N_SEQ + r) * ks + h * HDIM)[c];
    }
    __syncthreads();

    const int d = tid & 63, part = tid >> 6;
    for (int n = 0; n < N_SEQ; ++n) {
        if (tid < 32)
            reinterpret_cast<u32*>(qsm)[tid] =
                reinterpret_cast<const u32*>(Q + (size_t)(b * N_SEQ + n) * qs + h * HDIM)[tid];
        __syncthreads();

        float loc = -3.0e38f;
        for (int m = tid; m < N_SEQ; m += 256) {
            float s = 0.f;
#pragma unroll
            for (int dd = 0; dd < 64; ++dd)
                s += b2f(qsm[dd]) * b2f(Ks[m * 66 + dd]);
            s *= 0.125f;
            sc[m] = s;
            loc = fmaxf(loc, s);
        }
        const float mx = block_red<true>(loc, scratch, tid);
        float ls = 0.f;
        for (int m = tid; m < N_SEQ; m += 256) {
            float p = expf(sc[m] - mx);
            sc[m] = p; ls += p;
        }
        const float inv = 1.f / block_red<false>(ls, scratch, tid);

        if (asum) {
            for (int m = tid; m < N_SEQ; m += 256)
                atomicAdd(&asum[((size_t)b * N_SEQ + n) * N_SEQ + m], sc[m] * inv);
        }

        float accv = 0.f;
        for (int m = part; m < N_SEQ; m += 4)
            accv += sc[m] * b2f(Vp[(size_t)(b * N_SEQ + m) * vs + h * HDIM + d]);
        red[tid] = accv;
        __syncthreads();
        if (tid < 64) {
            float o = (red[tid] + red[tid + 64] + red[tid + 128] + red[tid + 192]) * inv;
            O[(size_t)(b * N_SEQ + n) * CDIM + h * HDIM + tid] = f2b(o);
        }
        __syncthreads();
    }
}

// ---------------------------------------------------------------------------
// small elementwise kernels (dtype-flexible on raw inputs / outputs)
// ---------------------------------------------------------------------------
__global__ __launch_bounds__(256)
void init_kernel(const void* __restrict__ src, const void* __restrict__ tgt,
                 const void* __restrict__ pos, float* __restrict__ sa,
                 float* __restrict__ ta, const u32* __restrict__ flag)
{
    const u32 i = blockIdx.x * 256 + threadIdx.x;
    const u32 p = i % (u32)(N_SEQ * CDIM);
    float sv, tv, pv;
    if (*flag) {
        sv = b2f(((const u16*)src)[i]); tv = b2f(((const u16*)tgt)[i]); pv = b2f(((const u16*)pos)[p]);
    } else {
        sv = ((const float*)src)[i];    tv = ((const float*)tgt)[i];    pv = ((const float*)pos)[p];
    }
    sa[i] = sv + pv;
    ta[i] = tv;
}

__global__ __launch_bounds__(256)
void zero_kernel(float* __restrict__ p, int n)
{
    const int i = blockIdx.x * 256 + threadIdx.x;
    if (i < n) p[i] = 0.f;
}

__global__ __launch_bounds__(256)
void gate_kernel(const float* __restrict__ asum, float* __restrict__ gate)
{
    const int b = blockIdx.x;
    for (int m = threadIdx.x; m < N_SEQ; m += 256) {
        float s = 0.f;
        for (int q = 0; q < N_SEQ; ++q)
            s += asum[((size_t)b * N_SEQ + q) * N_SEQ + m];
        s *= (1.f / 257.f);
        gate[b * N_SEQ + m] = 1.f / (1.f + expf(-s));
    }
}

__global__ __launch_bounds__(256)
void final_kernel(const float* __restrict__ sa, const float* __restrict__ ta,
                  const u16* __restrict__ saw, const float* __restrict__ gate,
                  void* __restrict__ osrc_v, const u32* __restrict__ flag)
{
    const u32 i = blockIdx.x * 256 + threadIdx.x;
    const int c  = i % CDIM;
    const int bn = i / CDIM;
    const float so = sa[i];
    const float to = ta[i] * (1.f + b2f(saw[c]) * gate[bn]);
    const size_t BNC = (size_t)MROWS * CDIM;
    if (*flag) {
        u16* o = (u16*)osrc_v;
        o[i] = f2b(so); o[BNC + i] = f2b(to);
    } else {
        float* o = (float*)osrc_v;
        o[i] = so; o[BNC + i] = to;
    }
}

__global__ __launch_bounds__(256)
void attm_kernel(const float* __restrict__ asum, void* __restrict__ out_v,
                 const u32* __restrict__ flag)
{
    const u32 i = blockIdx.x * 256 + threadIdx.x;   // < 64*256*256
    const int b = i >> 16;
    const int r = (i >> 8) & 255;
    const int c = i & 255;
    const float v = asum[((size_t)b * N_SEQ + (r + 1)) * N_SEQ + (c + 1)];
    const size_t off = 2 * (size_t)MROWS * CDIM;
    if (*flag) ((u16*)out_v)[off + i] = f2b(v);
    else       ((float*)out_v)[off + i] = v;
}

// ---------------------------------------------------------------------------
extern "C" void kernel_launch(void* const* d_in, const int* in_sizes, int n_in,
                              void* d_out, int out_size, void* d_ws, size_t ws_size,
                              hipStream_t stream)
{
    const void* src    = d_in[0];
    const void* tgt    = d_in[1];
    const void* pos    = d_in[17];

    const int M = MROWS;                       // 16448
    const size_t BNC = (size_t)M * CDIM;       // 12,632,064

    // workspace layout (~289 MiB)
    float* SA   = (float*)d_ws;                // fp32 src residual
    float* TA   = SA + BNC;                    // fp32 tgt residual
    u16*   Cb   = (u16*)(TA + BNC);            // bf16 srct
    u16*   Db   = Cb + BNC;                    // bf16 tmp (LN out / attn out)
    u16*   Eb   = Db + BNC;                    // bf16 4*BNC (QKV / hidden)
    float* ASUM = (float*)(Eb + 4 * BNC);      // B*N*N fp32
    float* GATE = ASUM + (size_t)BATCH * N_SEQ * N_SEQ;
    u16*   WB   = (u16*)(GATE + (size_t)BATCH * N_SEQ); // canonical bf16 weights
    // WB sub-layout (u16 element counts)
    u16* w_sqkv   = WB;                 // 1,769,472
    u16* w_sproj  = w_sqkv  + 1769472;  //   589,824
    u16* w_sprojb = w_sproj + 589824;   //       768
    u16* w_cqkv   = w_sprojb + 768;     // 1,769,472
    u16* w_cproj  = w_cqkv  + 1769472;  //   589,824
    u16* w_cprojb = w_cproj + 589824;   //       768
    u16* w_g1     = w_cprojb + 768;     //       768
    u16* w_b1     = w_g1 + 768;
    u16* w_g2     = w_b1 + 768;
    u16* w_b2     = w_g2 + 768;
    u16* w_fc1    = w_b2 + 768;         // 2,359,296
    u16* w_fc1b   = w_fc1 + 2359296;    //     3,072
    u16* w_fc2    = w_fc1b + 3072;      // 2,359,296
    u16* w_fc2b   = w_fc2 + 2359296;    //       768
    u16* w_saw    = w_fc2b + 768;       //       768
    u32* FLAG     = (u32*)(w_saw + 768);
    if (ws_size < (size_t)((char*)(FLAG + 4) - (char*)d_ws)) return;

    const dim3 blk(256, 1, 1);
    const int gM = (M + 127) / 128;            // 129

    detect_kernel<<<dim3(1), dim3(64), 0, stream>>>((const u16*)d_in[8], FLAG);

    auto conv = [&](int idx, u16* dst, int n) {
        conv_kernel<<<dim3((n + 255) / 256), blk, 0, stream>>>(d_in[idx], dst, n, FLAG);
    };
    conv(2,  w_sqkv,   1769472);
    conv(3,  w_sproj,  589824);
    conv(4,  w_sprojb, 768);
    conv(5,  w_cqkv,   1769472);
    conv(6,  w_cproj,  589824);
    conv(7,  w_cprojb, 768);
    conv(8,  w_g1,     768);
    conv(9,  w_b1,     768);
    conv(10, w_g2,     768);
    conv(11, w_b2,     768);
    conv(12, w_fc1,    2359296);
    conv(13, w_fc1b,   3072);
    conv(14, w_fc2,    2359296);
    conv(15, w_fc2b,   768);
    conv(16, w_saw,    768);

    init_kernel<<<dim3((u32)(BNC / 256)), blk, 0, stream>>>(src, tgt, pos, SA, TA, FLAG);

    // ---- src: self-attn + MLP ----
    ln_kernel<float><<<dim3(M), blk, 0, stream>>>(SA, w_g1, w_b1, Db);
    gemm_kernel<0><<<dim3(2304 / 128, gM), blk, 0, stream>>>(Db, w_sqkv, nullptr, Eb, nullptr, M, 2304, CDIM);
    attn_kernel<<<dim3(HEADS, BATCH), blk, 0, stream>>>(Eb, 2304, Eb + 768, 2304, Eb + 1536, 2304, Db, nullptr);
    gemm_kernel<2><<<dim3(6, gM), blk, 0, stream>>>(Db, w_sproj, w_sprojb, Cb, SA, M, CDIM, CDIM);
    ln_kernel<u16><<<dim3(M), blk, 0, stream>>>(Cb, w_g2, w_b2, Db);
    gemm_kernel<1><<<dim3(HIDDEN / 128, gM), blk, 0, stream>>>(Db, w_fc1, w_fc1b, Eb, nullptr, M, HIDDEN, CDIM);
    gemm_kernel<4><<<dim3(6, gM), blk, 0, stream>>>(Eb, w_fc2, w_fc2b, nullptr, SA, M, CDIM, HIDDEN);

    // ---- tgt: self-attn + MLP ----
    ln_kernel<float><<<dim3(M), blk, 0, stream>>>(TA, w_g1, w_b1, Db);
    gemm_kernel<0><<<dim3(2304 / 128, gM), blk, 0, stream>>>(Db, w_sqkv, nullptr, Eb, nullptr, M, 2304, CDIM);
    attn_kernel<<<dim3(HEADS, BATCH), blk, 0, stream>>>(Eb, 2304, Eb + 768, 2304, Eb + 1536, 2304, Db, nullptr);
    gemm_kernel<2><<<dim3(6, gM), blk, 0, stream>>>(Db, w_sproj, w_sprojb, Cb, TA, M, CDIM, CDIM);
    ln_kernel<u16><<<dim3(M), blk, 0, stream>>>(Cb, w_g2, w_b2, Db);
    gemm_kernel<1><<<dim3(HIDDEN / 128, gM), blk, 0, stream>>>(Db, w_fc1, w_fc1b, Eb, nullptr, M, HIDDEN, CDIM);
    gemm_kernel<4><<<dim3(6, gM), blk, 0, stream>>>(Eb, w_fc2, w_fc2b, nullptr, TA, M, CDIM, HIDDEN);

    // ---- cross-attn + MLP (on src), gate for tgt ----
    u16* EKV = Eb + BNC;
    ln_kernel<float><<<dim3(M), blk, 0, stream>>>(SA, w_g1, w_b1, Db);
    gemm_kernel<0><<<dim3(6, gM), blk, 0, stream>>>(Db, w_cqkv, nullptr, Eb, nullptr, M, CDIM, CDIM);
    ln_kernel<float><<<dim3(M), blk, 0, stream>>>(TA, w_g1, w_b1, Db);
    gemm_kernel<0><<<dim3(12, gM), blk, 0, stream>>>(Db, w_cqkv + 768 * 768, nullptr, EKV, nullptr, M, 1536, CDIM);
    const int asum_n = BATCH * N_SEQ * N_SEQ;
    zero_kernel<<<dim3((asum_n + 255) / 256), blk, 0, stream>>>(ASUM, asum_n);
    attn_kernel<<<dim3(HEADS, BATCH), blk, 0, stream>>>(Eb, 768, EKV, 1536, EKV + 768, 1536, Db, ASUM);
    gemm_kernel<3><<<dim3(6, gM), blk, 0, stream>>>(Db, w_cproj, w_cprojb, Cb, SA, M, CDIM, CDIM);
    ln_kernel<u16><<<dim3(M), blk, 0, stream>>>(Cb, w_g2, w_b2, Db);
    gemm_kernel<1><<<dim3(HIDDEN / 128, gM), blk, 0, stream>>>(Db, w_fc1, w_fc1b, Eb, nullptr, M, HIDDEN, CDIM);
    gemm_kernel<4><<<dim3(6, gM), blk, 0, stream>>>(Eb, w_fc2, w_fc2b, nullptr, SA, M, CDIM, HIDDEN);

    // ---- outputs ----
    gate_kernel<<<dim3(BATCH), blk, 0, stream>>>(ASUM, GATE);
    final_kernel<<<dim3((u32)(BNC / 256)), blk, 0, stream>>>(SA, TA, w_saw, GATE, d_out, FLAG);
    attm_kernel<<<dim3(BATCH * 256 * 256 / 256), blk, 0, stream>>>(ASUM, d_out, FLAG);
}

// Round 3
// 2692.845 us; speedup vs baseline: 4.1007x; 4.1007x over previous
//
#include <hip/hip_runtime.h>

#define N_SEQ  257
#define BATCH  64
#define CDIM   768
#define HEADS  12
#define HDIM   64
#define HIDDEN 3072
#define MROWS  (BATCH * N_SEQ)   // 16448

typedef unsigned short u16;
typedef unsigned int   u32;
typedef __bf16 bf16x8 __attribute__((ext_vector_type(8)));
typedef float  f32x4  __attribute__((ext_vector_type(4)));

__device__ __forceinline__ float b2f(u16 u) { u32 x = ((u32)u) << 16; return __uint_as_float(x); }
__device__ __forceinline__ u16   f2b(float f) {
    u32 x = __float_as_uint(f);
    u32 r = (x + 0x7fffu + ((x >> 16) & 1u)) >> 16;  // round-nearest-even
    return (u16)r;
}
__device__ __forceinline__ float ldf(const float x) { return x; }
__device__ __forceinline__ float ldf(const u16 x)   { return b2f(x); }

__device__ __forceinline__ float geluf(float x) { return 0.5f * x * (1.f + erff(x * 0.70710678118654752f)); }
// arf(x) = (e^x - e^-x)/(e^x + e^-x-4); negative clamped to 0. For x>0 multiply
// num/den by e^-x: (1 - e^-2x)/(1 + e^-2x-4) -- overflow-proof for all finite x.
__device__ __forceinline__ float arff(float x) {
    if (x <= 0.f) return 0.f;
    float a = expf(-2.f * x);
    float c = expf(-2.f * x - 4.f);
    return (1.f - a) / (1.f + c);
}

template<bool MAXOP>
__device__ __forceinline__ float block_red(float v, float* scratch, int tid) {
#pragma unroll
    for (int off = 32; off > 0; off >>= 1) {
        float o = __shfl_down(v, off, 64);
        v = MAXOP ? fmaxf(v, o) : v + o;
    }
    if ((tid & 63) == 0) scratch[tid >> 6] = v;
    __syncthreads();
    float r = MAXOP ? fmaxf(fmaxf(scratch[0], scratch[1]), fmaxf(scratch[2], scratch[3]))
                    : (scratch[0] + scratch[1]) + (scratch[2] + scratch[3]);
    __syncthreads();
    return r;
}

// ---------------------------------------------------------------------------
// dtype detection: norm1_g is all-ones. bf16(1.0) halfword = 0x3F80;
// fp32(1.0f) low halfword = 0x0000. flag: 1 = bf16 inputs, 0 = fp32 inputs.
// ---------------------------------------------------------------------------
__global__ void detect_kernel(const u16* __restrict__ g1, u32* __restrict__ flag)
{
    if (threadIdx.x == 0 && blockIdx.x == 0) *flag = (g1[0] == 0x3F80u) ? 1u : 0u;
}

__global__ __launch_bounds__(256)
void conv_kernel(const void* __restrict__ s, u16* __restrict__ d, int n,
                 const u32* __restrict__ flag)
{
    const int i = blockIdx.x * 256 + threadIdx.x;
    if (i >= n) return;
    if (*flag) d[i] = ((const u16*)s)[i];
    else       d[i] = f2b(((const float*)s)[i]);
}

// ---------------------------------------------------------------------------
// GEMM: out[m, n] = sum_k A[m,k] * W[n,k]   (A: MxK bf16, W: NxK bf16)
// 128x128 tile, BK=32, 4 waves each computing 64x64 via 4x4 mfma 16x16x32.
// EP: 0 plain(+bias), 1 gelu(+bias), 2 bias+write C+resid+=, 3 arf+write C+resid+=, 4 bias+resid+= only
// ---------------------------------------------------------------------------
#define LDSW 40   // padded LDS row stride in bf16 (80 B, 16B aligned, breaks bank conflicts)

template<int EP>
__global__ __launch_bounds__(256)
void gemm_kernel(const u16* __restrict__ A, const u16* __restrict__ W,
                 const u16* __restrict__ bias, u16* __restrict__ Co,
                 float* __restrict__ resid, int M, int Ncols, int K)
{
    __shared__ __align__(16) u16 sA[128 * LDSW];
    __shared__ __align__(16) u16 sB[128 * LDSW];
    const int tid  = threadIdx.x;
    const int bm0  = blockIdx.y * 128;
    const int n0   = blockIdx.x * 128;
    const int lane = tid & 63, wave = tid >> 6;
    const int wm = (wave >> 1) << 6;   // 0 / 64
    const int wn = (wave & 1) << 6;    // 0 / 64
    const int r16 = lane & 15, quad = lane >> 4;

    f32x4 acc[4][4] = {};

    for (int k0 = 0; k0 < K; k0 += 32) {
        __syncthreads();
#pragma unroll
        for (int it = 0; it < 2; ++it) {
            int c2  = tid + (it << 8);
            int row = c2 >> 2;
            int col = (c2 & 3) << 3;
            int gm  = bm0 + row; if (gm >= M) gm = M - 1;   // clamp (dup row; unused outputs guarded)
            *reinterpret_cast<uint4*>(&sA[row * LDSW + col]) =
                *reinterpret_cast<const uint4*>(A + (size_t)gm * K + k0 + col);
            *reinterpret_cast<uint4*>(&sB[row * LDSW + col]) =
                *reinterpret_cast<const uint4*>(W + (size_t)(n0 + row) * K + k0 + col);
        }
        __syncthreads();

        bf16x8 af[4], bfr[4];
#pragma unroll
        for (int i = 0; i < 4; ++i) {
            af[i]  = *reinterpret_cast<const bf16x8*>(&sA[(wm + i * 16 + r16) * LDSW + quad * 8]);
            bfr[i] = *reinterpret_cast<const bf16x8*>(&sB[(wn + i * 16 + r16) * LDSW + quad * 8]);
        }
#pragma unroll
        for (int i = 0; i < 4; ++i)
#pragma unroll
            for (int j = 0; j < 4; ++j)
                acc[i][j] = __builtin_amdgcn_mfma_f32_16x16x32_bf16(af[i], bfr[j], acc[i][j], 0, 0, 0);
    }

    // epilogue: lane holds D[row = quad*4+reg][col = lane&15] per 16x16 tile
#pragma unroll
    for (int i = 0; i < 4; ++i) {
#pragma unroll
        for (int j = 0; j < 4; ++j) {
            const int gn = n0 + wn + j * 16 + r16;
            const float bv = bias ? b2f(bias[gn]) : 0.f;
#pragma unroll
            for (int r = 0; r < 4; ++r) {
                const int gm = bm0 + wm + i * 16 + quad * 4 + r;
                if (gm < M) {
                    float v = acc[i][j][r] + bv;
                    const size_t oidx = (size_t)gm * Ncols + gn;
                    if (EP == 1) v = geluf(v);
                    if (EP == 3) v = arff(v);
                    if (EP == 0 || EP == 1) Co[oidx] = f2b(v);
                    if (EP == 2 || EP == 3) { Co[oidx] = f2b(v); resid[oidx] += v; }
                    if (EP == 4) resid[oidx] += v;
                }
            }
        }
    }
}

// ---------------------------------------------------------------------------
// LayerNorm over C=768; one block per row; input fp32 or bf16, output bf16
// ---------------------------------------------------------------------------
template<typename T>
__global__ __launch_bounds__(256)
void ln_kernel(const T* __restrict__ x, const u16* __restrict__ g,
               const u16* __restrict__ be, u16* __restrict__ y)
{
    __shared__ float scratch[4];
    const int row = blockIdx.x, tid = threadIdx.x;
    const size_t base = (size_t)row * CDIM;
    float v[3];
#pragma unroll
    for (int i = 0; i < 3; ++i) v[i] = ldf(x[base + tid + i * 256]);
    float mean = block_red<false>(v[0] + v[1] + v[2], scratch, tid) * (1.f / 768.f);
    float d0 = v[0] - mean, d1 = v[1] - mean, d2 = v[2] - mean;
    float var = block_red<false>(d0 * d0 + d1 * d1 + d2 * d2, scratch, tid) * (1.f / 768.f);
    float rstd = rsqrtf(var + 1e-5f);
#pragma unroll
    for (int i = 0; i < 3; ++i) {
        int c = tid + i * 256;
        y[base + c] = f2b((v[i] - mean) * rstd * b2f(g[c]) + b2f(be[c]));
    }
}

// ---------------------------------------------------------------------------
// MFMA attention. Block = (n-tile of 64 Q rows, h, b); 4 waves, each owning
// 16 Q rows. Full S[16x320] per wave in registers (20 f32x4). Q + V^T staged
// once in LDS; K per 64-key tile; P round-trips LDS (C-layout -> A-layout).
// Keys >= 257 masked to -3e38 before softmax. O normalized at the end.
// Optional asum[b,n,m] += p (normalized) for cross-attn.
// ---------------------------------------------------------------------------
__global__ __launch_bounds__(256)
void attn_mfma_kernel(const u16* __restrict__ Q, int qs,
                      const u16* __restrict__ Kp, int ks,
                      const u16* __restrict__ Vp, int vs,
                      u16* __restrict__ O, float* __restrict__ asum)
{
    __shared__ __align__(16) u16 Qs[64 * 72];    //  9.2 KB
    __shared__ __align__(16) u16 KP[64 * 72];    //  9.2 KB (K-tile, then P)
    __shared__ __align__(16) u16 Vt[64 * 328];   // 42.0 KB (V^T, 320 keys padded)
    const int tid = threadIdx.x;
    const int n0 = blockIdx.x * 64;
    const int h  = blockIdx.y, b = blockIdx.z;
    const int lane = tid & 63, w = tid >> 6;
    const int r16 = lane & 15, quad = lane >> 4;

    // stage Q tile (rows clamped; clamped rows = dup of row 256, finite)
    {
        int id = tid;
#pragma unroll
        for (int it = 0; it < 2; ++it, id += 256) {
            int row = id >> 3, dc = (id & 7) << 3;
            int gn = n0 + row; if (gn > 256) gn = 256;
            *reinterpret_cast<uint4*>(&Qs[row * 72 + dc]) =
                *reinterpret_cast<const uint4*>(Q + (size_t)(b * N_SEQ + gn) * qs + h * HDIM + dc);
        }
    }
    // stage V transposed: Vt[d][m], m in [0,320)
    for (int id = tid; id < 320 * 8; id += 256) {
        int m = id >> 3, dc = (id & 7) << 3;
        int gm = m > 256 ? 256 : m;
        uint4 v4 = *reinterpret_cast<const uint4*>(Vp + (size_t)(b * N_SEQ + gm) * vs + h * HDIM + dc);
        const u16* vv = reinterpret_cast<const u16*>(&v4);
#pragma unroll
        for (int j = 0; j < 8; ++j) Vt[(dc + j) * 328 + m] = vv[j];
    }
    __syncthreads();

    const bf16x8 af0 = *reinterpret_cast<const bf16x8*>(&Qs[(w * 16 + r16) * 72 + quad * 8]);
    const bf16x8 af1 = *reinterpret_cast<const bf16x8*>(&Qs[(w * 16 + r16) * 72 + 32 + quad * 8]);

    f32x4 S[20];
#pragma unroll
    for (int t = 0; t < 20; ++t) S[t] = (f32x4){0.f, 0.f, 0.f, 0.f};

    // ---- QK^T over 5 key tiles ----
    for (int kt = 0; kt < 5; ++kt) {
        __syncthreads();
        int id = tid;
#pragma unroll
        for (int it = 0; it < 2; ++it, id += 256) {
            int row = id >> 3, dc = (id & 7) << 3;
            int gm = kt * 64 + row; if (gm > 256) gm = 256;
            *reinterpret_cast<uint4*>(&KP[row * 72 + dc]) =
                *reinterpret_cast<const uint4*>(Kp + (size_t)(b * N_SEQ + gm) * ks + h * HDIM + dc);
        }
        __syncthreads();
#pragma unroll
        for (int s = 0; s < 4; ++s) {
            bf16x8 b0 = *reinterpret_cast<const bf16x8*>(&KP[(s * 16 + r16) * 72 + quad * 8]);
            bf16x8 b1 = *reinterpret_cast<const bf16x8*>(&KP[(s * 16 + r16) * 72 + 32 + quad * 8]);
            S[kt * 4 + s] = __builtin_amdgcn_mfma_f32_16x16x32_bf16(af0, b0, S[kt * 4 + s], 0, 0, 0);
            S[kt * 4 + s] = __builtin_amdgcn_mfma_f32_16x16x32_bf16(af1, b1, S[kt * 4 + s], 0, 0, 0);
        }
    }
    __syncthreads();   // all waves done reading KP as K

    // ---- softmax per Q row (row = quad*4+r; keys across tiles x lanes 0..15) ----
    float inv[4];
#pragma unroll
    for (int r = 0; r < 4; ++r) {
        float m_ = -3.0e38f;
#pragma unroll
        for (int t = 0; t < 20; ++t) {
            int key = t * 16 + r16;
            float v = S[t][r] * 0.125f;
            if (key >= 257) v = -3.0e38f;
            S[t][r] = v;
            m_ = fmaxf(m_, v);
        }
#pragma unroll
        for (int msk = 1; msk < 16; msk <<= 1) m_ = fmaxf(m_, __shfl_xor(m_, msk, 64));
        float s_ = 0.f;
#pragma unroll
        for (int t = 0; t < 20; ++t) {
            float p = __expf(S[t][r] - m_);
            S[t][r] = p; s_ += p;
        }
#pragma unroll
        for (int msk = 1; msk < 16; msk <<= 1) s_ += __shfl_xor(s_, msk, 64);
        inv[r] = 1.f / s_;
    }

    // ---- cross-attn: accumulate normalized probs into asum ----
    if (asum) {
#pragma unroll
        for (int r = 0; r < 4; ++r) {
            const int n = n0 + w * 16 + quad * 4 + r;
            if (n < N_SEQ) {
#pragma unroll
                for (int t = 0; t < 20; ++t) {
                    int key = t * 16 + r16;
                    if (key < N_SEQ)
                        atomicAdd(&asum[((size_t)b * N_SEQ + n) * N_SEQ + key], S[t][r] * inv[r]);
                }
            }
        }
    }

    // ---- PV: per key tile, P -> LDS (own 16-row region), mfma vs V^T ----
    f32x4 O4[4];
#pragma unroll
    for (int s = 0; s < 4; ++s) O4[s] = (f32x4){0.f, 0.f, 0.f, 0.f};

    for (int kt = 0; kt < 5; ++kt) {
#pragma unroll
        for (int ts = 0; ts < 4; ++ts)
#pragma unroll
            for (int r = 0; r < 4; ++r)
                KP[(w * 16 + quad * 4 + r) * 72 + ts * 16 + r16] = f2b(S[kt * 4 + ts][r]);
        // same-wave LDS ops execute in order: no barrier needed (per-wave region)
        bf16x8 p0 = *reinterpret_cast<const bf16x8*>(&KP[(w * 16 + r16) * 72 + quad * 8]);
        bf16x8 p1 = *reinterpret_cast<const bf16x8*>(&KP[(w * 16 + r16) * 72 + 32 + quad * 8]);
#pragma unroll
        for (int s = 0; s < 4; ++s) {
            bf16x8 v0 = *reinterpret_cast<const bf16x8*>(&Vt[(s * 16 + r16) * 328 + kt * 64 + quad * 8]);
            bf16x8 v1 = *reinterpret_cast<const bf16x8*>(&Vt[(s * 16 + r16) * 328 + kt * 64 + 32 + quad * 8]);
            O4[s] = __builtin_amdgcn_mfma_f32_16x16x32_bf16(p0, v0, O4[s], 0, 0, 0);
            O4[s] = __builtin_amdgcn_mfma_f32_16x16x32_bf16(p1, v1, O4[s], 0, 0, 0);
        }
    }

    // ---- store O (row = quad*4+r, col d = s*16+r16) ----
#pragma unroll
    for (int s = 0; s < 4; ++s) {
#pragma unroll
        for (int r = 0; r < 4; ++r) {
            const int n = n0 + w * 16 + quad * 4 + r;
            if (n < N_SEQ)
                O[(size_t)(b * N_SEQ + n) * CDIM + h * HDIM + s * 16 + r16] = f2b(O4[s][r] * inv[r]);
        }
    }
}

// ---------------------------------------------------------------------------
// small elementwise kernels (dtype-flexible on raw inputs / outputs)
// ---------------------------------------------------------------------------
__global__ __launch_bounds__(256)
void init_kernel(const void* __restrict__ src, const void* __restrict__ tgt,
                 const void* __restrict__ pos, float* __restrict__ sa,
                 float* __restrict__ ta, const u32* __restrict__ flag)
{
    const u32 i = blockIdx.x * 256 + threadIdx.x;
    const u32 p = i % (u32)(N_SEQ * CDIM);
    float sv, tv, pv;
    if (*flag) {
        sv = b2f(((const u16*)src)[i]); tv = b2f(((const u16*)tgt)[i]); pv = b2f(((const u16*)pos)[p]);
    } else {
        sv = ((const float*)src)[i];    tv = ((const float*)tgt)[i];    pv = ((const float*)pos)[p];
    }
    sa[i] = sv + pv;
    ta[i] = tv;
}

__global__ __launch_bounds__(256)
void zero_kernel(float* __restrict__ p, int n)
{
    const int i = blockIdx.x * 256 + threadIdx.x;
    if (i < n) p[i] = 0.f;
}

__global__ __launch_bounds__(256)
void gate_kernel(const float* __restrict__ asum, float* __restrict__ gate)
{
    const int b = blockIdx.x;
    for (int m = threadIdx.x; m < N_SEQ; m += 256) {
        float s = 0.f;
        for (int q = 0; q < N_SEQ; ++q)
            s += asum[((size_t)b * N_SEQ + q) * N_SEQ + m];
        s *= (1.f / 257.f);
        gate[b * N_SEQ + m] = 1.f / (1.f + expf(-s));
    }
}

__global__ __launch_bounds__(256)
void final_kernel(const float* __restrict__ sa, const float* __restrict__ ta,
                  const u16* __restrict__ saw, const float* __restrict__ gate,
                  void* __restrict__ osrc_v, const u32* __restrict__ flag)
{
    const u32 i = blockIdx.x * 256 + threadIdx.x;
    const int c  = i % CDIM;
    const int bn = i / CDIM;
    const float so = sa[i];
    const float to = ta[i] * (1.f + b2f(saw[c]) * gate[bn]);
    const size_t BNC = (size_t)MROWS * CDIM;
    if (*flag) {
        u16* o = (u16*)osrc_v;
        o[i] = f2b(so); o[BNC + i] = f2b(to);
    } else {
        float* o = (float*)osrc_v;
        o[i] = so; o[BNC + i] = to;
    }
}

__global__ __launch_bounds__(256)
void attm_kernel(const float* __restrict__ asum, void* __restrict__ out_v,
                 const u32* __restrict__ flag)
{
    const u32 i = blockIdx.x * 256 + threadIdx.x;   // < 64*256*256
    const int b = i >> 16;
    const int r = (i >> 8) & 255;
    const int c = i & 255;
    const float v = asum[((size_t)b * N_SEQ + (r + 1)) * N_SEQ + (c + 1)];
    const size_t off = 2 * (size_t)MROWS * CDIM;
    if (*flag) ((u16*)out_v)[off + i] = f2b(v);
    else       ((float*)out_v)[off + i] = v;
}

// ---------------------------------------------------------------------------
extern "C" void kernel_launch(void* const* d_in, const int* in_sizes, int n_in,
                              void* d_out, int out_size, void* d_ws, size_t ws_size,
                              hipStream_t stream)
{
    const void* src    = d_in[0];
    const void* tgt    = d_in[1];
    const void* pos    = d_in[17];

    const int M = MROWS;                       // 16448
    const size_t BNC = (size_t)M * CDIM;       // 12,632,064

    // workspace layout (~289 MiB)
    float* SA   = (float*)d_ws;                // fp32 src residual
    float* TA   = SA + BNC;                    // fp32 tgt residual
    u16*   Cb   = (u16*)(TA + BNC);            // bf16 srct
    u16*   Db   = Cb + BNC;                    // bf16 tmp (LN out / attn out)
    u16*   Eb   = Db + BNC;                    // bf16 4*BNC (QKV / hidden)
    float* ASUM = (float*)(Eb + 4 * BNC);      // B*N*N fp32
    float* GATE = ASUM + (size_t)BATCH * N_SEQ * N_SEQ;
    u16*   WB   = (u16*)(GATE + (size_t)BATCH * N_SEQ); // canonical bf16 weights
    // WB sub-layout (u16 element counts)
    u16* w_sqkv   = WB;                 // 1,769,472
    u16* w_sproj  = w_sqkv  + 1769472;  //   589,824
    u16* w_sprojb = w_sproj + 589824;   //       768
    u16* w_cqkv   = w_sprojb + 768;     // 1,769,472
    u16* w_cproj  = w_cqkv  + 1769472;  //   589,824
    u16* w_cprojb = w_cproj + 589824;   //       768
    u16* w_g1     = w_cprojb + 768;     //       768
    u16* w_b1     = w_g1 + 768;
    u16* w_g2     = w_b1 + 768;
    u16* w_b2     = w_g2 + 768;
    u16* w_fc1    = w_b2 + 768;         // 2,359,296
    u16* w_fc1b   = w_fc1 + 2359296;    //     3,072
    u16* w_fc2    = w_fc1b + 3072;      // 2,359,296
    u16* w_fc2b   = w_fc2 + 2359296;    //       768
    u16* w_saw    = w_fc2b + 768;       //       768
    u32* FLAG     = (u32*)(w_saw + 768);
    if (ws_size < (size_t)((char*)(FLAG + 4) - (char*)d_ws)) return;

    const dim3 blk(256, 1, 1);
    const int gM = (M + 127) / 128;            // 129
    const dim3 agrid(5, HEADS, BATCH);         // 64-row Q tiles x heads x batch

    detect_kernel<<<dim3(1), dim3(64), 0, stream>>>((const u16*)d_in[8], FLAG);

    auto conv = [&](int idx, u16* dst, int n) {
        conv_kernel<<<dim3((n + 255) / 256), blk, 0, stream>>>(d_in[idx], dst, n, FLAG);
    };
    conv(2,  w_sqkv,   1769472);
    conv(3,  w_sproj,  589824);
    conv(4,  w_sprojb, 768);
    conv(5,  w_cqkv,   1769472);
    conv(6,  w_cproj,  589824);
    conv(7,  w_cprojb, 768);
    conv(8,  w_g1,     768);
    conv(9,  w_b1,     768);
    conv(10, w_g2,     768);
    conv(11, w_b2,     768);
    conv(12, w_fc1,    2359296);
    conv(13, w_fc1b,   3072);
    conv(14, w_fc2,    2359296);
    conv(15, w_fc2b,   768);
    conv(16, w_saw,    768);

    init_kernel<<<dim3((u32)(BNC / 256)), blk, 0, stream>>>(src, tgt, pos, SA, TA, FLAG);

    // ---- src: self-attn + MLP ----
    ln_kernel<float><<<dim3(M), blk, 0, stream>>>(SA, w_g1, w_b1, Db);
    gemm_kernel<0><<<dim3(2304 / 128, gM), blk, 0, stream>>>(Db, w_sqkv, nullptr, Eb, nullptr, M, 2304, CDIM);
    attn_mfma_kernel<<<agrid, blk, 0, stream>>>(Eb, 2304, Eb + 768, 2304, Eb + 1536, 2304, Db, nullptr);
    gemm_kernel<2><<<dim3(6, gM), blk, 0, stream>>>(Db, w_sproj, w_sprojb, Cb, SA, M, CDIM, CDIM);
    ln_kernel<u16><<<dim3(M), blk, 0, stream>>>(Cb, w_g2, w_b2, Db);
    gemm_kernel<1><<<dim3(HIDDEN / 128, gM), blk, 0, stream>>>(Db, w_fc1, w_fc1b, Eb, nullptr, M, HIDDEN, CDIM);
    gemm_kernel<4><<<dim3(6, gM), blk, 0, stream>>>(Eb, w_fc2, w_fc2b, nullptr, SA, M, CDIM, HIDDEN);

    // ---- tgt: self-attn + MLP ----
    ln_kernel<float><<<dim3(M), blk, 0, stream>>>(TA, w_g1, w_b1, Db);
    gemm_kernel<0><<<dim3(2304 / 128, gM), blk, 0, stream>>>(Db, w_sqkv, nullptr, Eb, nullptr, M, 2304, CDIM);
    attn_mfma_kernel<<<agrid, blk, 0, stream>>>(Eb, 2304, Eb + 768, 2304, Eb + 1536, 2304, Db, nullptr);
    gemm_kernel<2><<<dim3(6, gM), blk, 0, stream>>>(Db, w_sproj, w_sprojb, Cb, TA, M, CDIM, CDIM);
    ln_kernel<u16><<<dim3(M), blk, 0, stream>>>(Cb, w_g2, w_b2, Db);
    gemm_kernel<1><<<dim3(HIDDEN / 128, gM), blk, 0, stream>>>(Db, w_fc1, w_fc1b, Eb, nullptr, M, HIDDEN, CDIM);
    gemm_kernel<4><<<dim3(6, gM), blk, 0, stream>>>(Eb, w_fc2, w_fc2b, nullptr, TA, M, CDIM, HIDDEN);

    // ---- cross-attn + MLP (on src), gate for tgt ----
    u16* EKV = Eb + BNC;
    ln_kernel<float><<<dim3(M), blk, 0, stream>>>(SA, w_g1, w_b1, Db);
    gemm_kernel<0><<<dim3(6, gM), blk, 0, stream>>>(Db, w_cqkv, nullptr, Eb, nullptr, M, CDIM, CDIM);
    ln_kernel<float><<<dim3(M), blk, 0, stream>>>(TA, w_g1, w_b1, Db);
    gemm_kernel<0><<<dim3(12, gM), blk, 0, stream>>>(Db, w_cqkv + 768 * 768, nullptr, EKV, nullptr, M, 1536, CDIM);
    const int asum_n = BATCH * N_SEQ * N_SEQ;
    zero_kernel<<<dim3((asum_n + 255) / 256), blk, 0, stream>>>(ASUM, asum_n);
    attn_mfma_kernel<<<agrid, blk, 0, stream>>>(Eb, 768, EKV, 1536, EKV + 768, 1536, Db, ASUM);
    gemm_kernel<3><<<dim3(6, gM), blk, 0, stream>>>(Db, w_cproj, w_cprojb, Cb, SA, M, CDIM, CDIM);
    ln_kernel<u16><<<dim3(M), blk, 0, stream>>>(Cb, w_g2, w_b2, Db);
    gemm_kernel<1><<<dim3(HIDDEN / 128, gM), blk, 0, stream>>>(Db, w_fc1, w_fc1b, Eb, nullptr, M, HIDDEN, CDIM);
    gemm_kernel<4><<<dim3(6, gM), blk, 0, stream>>>(Eb, w_fc2, w_fc2b, nullptr, SA, M, CDIM, HIDDEN);

    // ---- outputs ----
    gate_kernel<<<dim3(BATCH), blk, 0, stream>>>(ASUM, GATE);
    final_kernel<<<dim3((u32)(BNC / 256)), blk, 0, stream>>>(SA, TA, w_saw, GATE, d_out, FLAG);
    attm_kernel<<<dim3(BATCH * 256 * 256 / 256), blk, 0, stream>>>(ASUM, d_out, FLAG);
}